// Round 1
// baseline (398.098 us; speedup 1.0000x reference)
//
#include <hip/hip_runtime.h>

// Problem constants (fixed by setup_inputs)
#define BB    16
#define NODES 64
#define HID   128
#define CC    256
#define HWP   16384   // H*W = 128*128

// ---------------------------------------------------------------------------
// Kernel A: per-batch attention vector.
//   s_hid[n] = x[b,n,:] . nfh            (softmax input; s_res cancels in softmax)
//   attn     = softmax_n(s_hid)
//   y[k]     = sum_n attn[n] * x[b,n,k]
//   val[b,c] = relu( sum_k y[k] * W[k,c] )
// One block per b, 256 threads.
// ---------------------------------------------------------------------------
__global__ __launch_bounds__(256) void attn_vec_kernel(
    const float* __restrict__ x,      // (B, NODES, HID)
    const float* __restrict__ nfh,    // (HID, 1)
    const float* __restrict__ w,      // (HID, C)
    float*       __restrict__ vals)   // (B, C) in d_ws
{
    __shared__ float s_part[NODES][4];
    __shared__ float attn[NODES];
    __shared__ float y[HID];

    const int b   = blockIdx.x;
    const int tid = threadIdx.x;

    // ---- step 1: partial dots for s_hid (4 threads per node, 32 elems each)
    {
        const int n = tid >> 2;   // 0..63
        const int q = tid & 3;    // 0..3
        const float* xp = x + ((size_t)b * NODES + n) * HID + q * 32;
        const float* fp = nfh + q * 32;
        float acc = 0.f;
        #pragma unroll
        for (int k = 0; k < 32; ++k) acc = fmaf(xp[k], fp[k], acc);
        s_part[n][q] = acc;
    }
    __syncthreads();

    // ---- step 2: softmax over 64 nodes in the first wave (wave = 64 lanes)
    if (tid < NODES) {
        float v = s_part[tid][0] + s_part[tid][1] + s_part[tid][2] + s_part[tid][3];
        float m = v;
        #pragma unroll
        for (int off = 32; off >= 1; off >>= 1)
            m = fmaxf(m, __shfl_xor(m, off, 64));
        float e = __expf(v - m);
        float ssum = e;
        #pragma unroll
        for (int off = 32; off >= 1; off >>= 1)
            ssum += __shfl_xor(ssum, off, 64);
        attn[tid] = e / ssum;
    }
    __syncthreads();

    // ---- step 3: y[k] = sum_n attn[n] * x[b,n,k]   (threads 0..127, coalesced)
    if (tid < HID) {
        const float* xb = x + (size_t)b * NODES * HID + tid;
        float acc = 0.f;
        #pragma unroll 8
        for (int n = 0; n < NODES; ++n)
            acc = fmaf(attn[n], xb[(size_t)n * HID], acc);
        y[tid] = acc;
    }
    __syncthreads();

    // ---- step 4: val[b,c] = relu(sum_k y[k] * W[k,c])  (c = tid, coalesced W)
    {
        float acc = 0.f;
        #pragma unroll 8
        for (int k = 0; k < HID; ++k)
            acc = fmaf(y[k], w[(size_t)k * CC + tid], acc);
        vals[b * CC + tid] = fmaxf(acc, 0.f);
    }
}

// ---------------------------------------------------------------------------
// Kernel B: broadcast fill. out[b,c,:,:] = vals[b,c].
// One block per (b,c) plane (4096 blocks); 256 threads x 16 float4 stores
// = 16384 floats = 64 KiB contiguous per block. Pure write stream.
// ---------------------------------------------------------------------------
__global__ __launch_bounds__(256) void broadcast_kernel(
    const float* __restrict__ vals,   // (B*C)
    float*       __restrict__ out)    // (B, C, H, W)
{
    const int bc = blockIdx.x;
    const float v = vals[bc];                     // uniform load per block
    const float4 v4 = make_float4(v, v, v, v);
    float4* base = (float4*)(out + (size_t)bc * HWP) + threadIdx.x;
    #pragma unroll
    for (int i = 0; i < HWP / (256 * 4); ++i)     // 16 iterations
        base[i * 256] = v4;
}

extern "C" void kernel_launch(void* const* d_in, const int* in_sizes, int n_in,
                              void* d_out, int out_size, void* d_ws, size_t ws_size,
                              hipStream_t stream) {
    // setup_inputs order:
    //   0: input            (1, B, NODES, HID) fp32
    //   1: res_feature      (B, C, H, W)       fp32   -- UNUSED (cancels in softmax)
    //   2: node_fea_for_res (C, 1)             fp32   -- UNUSED (cancels in softmax)
    //   3: node_fea_for_hidden (HID, 1)        fp32
    //   4: weight           (HID, C)           fp32
    const float* x   = (const float*)d_in[0];
    const float* nfh = (const float*)d_in[3];
    const float* w   = (const float*)d_in[4];
    float* vals = (float*)d_ws;       // B*C = 4096 floats = 16 KiB scratch
    float* out  = (float*)d_out;

    attn_vec_kernel<<<BB, 256, 0, stream>>>(x, nfh, w, vals);
    broadcast_kernel<<<BB * CC, 256, 0, stream>>>(vals, out);
}

// Round 2
// 395.083 us; speedup vs baseline: 1.0076x; 1.0076x over previous
//
#include <hip/hip_runtime.h>

// Problem constants (fixed by setup_inputs)
#define BB    16
#define NODES 64
#define HID   128
#define CC    256
#define HWP   16384   // H*W = 128*128

// ---------------------------------------------------------------------------
// Fused kernel: one block per (b,c) output plane.
//
// Math (softmax over nodes is invariant to the per-pixel s_res term, so the
// attention vector — and hence the output value — is constant over H*W):
//   s_hid[n] = x[b,n,:] . nfh
//   attn     = softmax_n(s_hid)
//   y[k]     = sum_n attn[n] * x[b,n,k]
//   val      = relu( sum_k y[k] * W[k,c] )
//   out[b,c,:,:] = val
//
// Per-block cost: ~16K FMA + 64 KiB of x reads (L2-resident after first
// touch per b; x[b] is 32 KiB, shared by 256 blocks) + 128 W loads.
// The 64 KiB contiguous plane fill dominates: pure streaming write.
// ---------------------------------------------------------------------------
__global__ __launch_bounds__(256) void fused_kernel(
    const float* __restrict__ x,      // (B, NODES, HID)
    const float* __restrict__ nfh,    // (HID, 1)
    const float* __restrict__ w,      // (HID, C)
    float*       __restrict__ out)    // (B, C, H, W)
{
    const int bc  = blockIdx.x;
    const int b   = bc >> 8;          // bc = b*C + c
    const int c   = bc & (CC - 1);
    const int tid = threadIdx.x;

    __shared__ float s_part[NODES][4];
    __shared__ float attn[NODES];
    __shared__ float prod[HID];
    __shared__ float s_val;

    // ---- step 1: partial dots for s_hid (4 threads per node, 32 elems each)
    {
        const int n = tid >> 2;       // 0..63
        const int q = tid & 3;        // 0..3
        const float* xp = x + ((size_t)b * NODES + n) * HID + q * 32;
        const float* fp = nfh + q * 32;
        float acc = 0.f;
        #pragma unroll
        for (int k = 0; k < 32; ++k) acc = fmaf(xp[k], fp[k], acc);
        s_part[n][q] = acc;
    }
    __syncthreads();

    // ---- step 2: softmax over 64 nodes in wave 0 (wave = 64 lanes)
    if (tid < NODES) {
        float v = s_part[tid][0] + s_part[tid][1] + s_part[tid][2] + s_part[tid][3];
        float m = v;
        #pragma unroll
        for (int off = 32; off >= 1; off >>= 1)
            m = fmaxf(m, __shfl_xor(m, off, 64));
        float e = __expf(v - m);
        float ssum = e;
        #pragma unroll
        for (int off = 32; off >= 1; off >>= 1)
            ssum += __shfl_xor(ssum, off, 64);
        attn[tid] = e / ssum;
    }
    __syncthreads();

    // ---- step 3: y[k] = sum_n attn[n]*x[b,n,k]; fold in W[k,c] immediately
    if (tid < HID) {
        const float* xb = x + (size_t)b * NODES * HID + tid;
        float acc = 0.f;
        #pragma unroll 8
        for (int n = 0; n < NODES; ++n)
            acc = fmaf(attn[n], xb[(size_t)n * HID], acc);
        prod[tid] = acc * w[(size_t)tid * CC + c];
    }
    __syncthreads();

    // ---- step 4: reduce 128 products in wave 0, relu, broadcast via LDS
    if (tid < 64) {
        float v = prod[tid] + prod[tid + 64];
        #pragma unroll
        for (int off = 32; off >= 1; off >>= 1)
            v += __shfl_xor(v, off, 64);
        if (tid == 0) s_val = fmaxf(v, 0.f);
    }
    __syncthreads();

    // ---- step 5: fill this (b,c) plane: 256 thr x 16 float4 = 64 KiB
    const float vv = s_val;
    const float4 v4 = make_float4(vv, vv, vv, vv);
    float4* base = (float4*)(out + (size_t)bc * HWP) + tid;
    #pragma unroll
    for (int i = 0; i < HWP / (256 * 4); ++i)   // 16 iterations
        base[i * 256] = v4;
}

extern "C" void kernel_launch(void* const* d_in, const int* in_sizes, int n_in,
                              void* d_out, int out_size, void* d_ws, size_t ws_size,
                              hipStream_t stream) {
    // setup_inputs order:
    //   0: input               (1, B, NODES, HID) fp32
    //   1: res_feature         (B, C, H, W)       fp32  -- UNUSED (cancels in softmax)
    //   2: node_fea_for_res    (C, 1)             fp32  -- UNUSED (cancels in softmax)
    //   3: node_fea_for_hidden (HID, 1)           fp32
    //   4: weight              (HID, C)           fp32
    const float* x   = (const float*)d_in[0];
    const float* nfh = (const float*)d_in[3];
    const float* w   = (const float*)d_in[4];
    float* out = (float*)d_out;

    fused_kernel<<<BB * CC, 256, 0, stream>>>(x, nfh, w, out);
}